// Round 5
// baseline (2731.684 us; speedup 1.0000x reference)
//
#include <hip/hip_runtime.h>
#include <stdint.h>

// SetAbstraction (PointNet++): B=4, N=8192, C=128, S=2048, K=32, R=0.1
// I/O f32. Ref = np/BLAS f32. FPS mirrors np.sum LTR order (verified exact,
// output 0 passes). Grouping sq = (cc + pp) - 2*dot with dot as an
// ASCENDING FMA chain (BLAS sgemm / Eigen gebp k-loop: acc=fma(a_k,b_k,acc)
// from 0; first step == rounded product). R2 falsified mul+add ascending,
// R4 falsified mul+add descending (np.einsum C-loop), R3 falsified f64.
// MLP via bf16 MFMA (value noise ~1e-2 << 6.4e-2 threshold).

typedef unsigned short u16;
typedef unsigned long long u64;
typedef __bf16 bf16x8 __attribute__((ext_vector_type(8)));
typedef float f32x4 __attribute__((ext_vector_type(4)));

#define NB 4
#define NPTS 8192
#define CH 128
#define SPTS 2048
#define KN 32
#define CINP 160   // 131 padded to 160 (5 k-steps of 32)

__device__ __forceinline__ u16 f2b(float f) {  // f32 -> bf16 RNE
    unsigned x = __float_as_uint(f);
    unsigned r = (x + 0x7fffu + ((x >> 16) & 1u)) >> 16;
    return (u16)r;
}
__device__ __forceinline__ u64 umin64(u64 a, u64 b) { return a < b ? a : b; }

// ---------------- transpose fea (B,C,N) f32 -> feaT (B,N,C) bf16 ----------------
__global__ __launch_bounds__(256) void ktrans(const float* __restrict__ fea,
                                              u16* __restrict__ feaT) {
    __shared__ u16 T[128][130];
    int blk = blockIdx.x;  // 4 b x 64 n-tiles
    int b = blk >> 6, nt = blk & 63;
    int n0 = nt * 128;
    int t = threadIdx.x;
#pragma unroll 4
    for (int it = 0; it < 64; ++it) {
        int idx = it * 256 + t;
        int c = idx >> 7, nl = idx & 127;
        T[nl][c] = f2b(fea[((size_t)(b * CH + c)) * NPTS + n0 + nl]);
    }
    __syncthreads();
#pragma unroll 4
    for (int it = 0; it < 64; ++it) {
        int idx = it * 256 + t;
        int nl = idx >> 7, c = idx & 127;
        feaT[((size_t)(b * NPTS + n0 + nl)) * CH + c] = T[nl][c];
    }
}

// ---------------- pp = |p|^2 (np.sum LTR), W pad to bf16 ----------------
__global__ __launch_bounds__(256) void kmisc(const float* __restrict__ coor,
                                             const float* __restrict__ W,
                                             float* __restrict__ pp,
                                             u16* __restrict__ Wpad) {
    int gid = blockIdx.x * 256 + threadIdx.x;
    if (blockIdx.x < 128) {
        int n = gid & 8191, b = gid >> 13;
        const float* cb = coor + b * 3 * NPTS;
        float x = cb[n], y = cb[NPTS + n], z = cb[2 * NPTS + n];
        pp[gid] = __fadd_rn(__fadd_rn(__fmul_rn(x, x), __fmul_rn(y, y)),
                            __fmul_rn(z, z));
    } else {
        int i = gid - 128 * 256;
        if (i < 256 * CINP) {
            int d = i / CINP, k = i - d * CINP;
            Wpad[i] = (k < 131) ? f2b(W[d * 131 + k]) : (u16)0;
        }
    }
}

// ---------------- FPS: 1 block (1024 thr) per batch (UNCHANGED: passing) ----------------
__global__ __launch_bounds__(1024) void kfps(const float* __restrict__ coor,
                                             int* __restrict__ fpsIdx,
                                             float* __restrict__ outCoor) {
    __shared__ float sx[NPTS], sy[NPTS], sz[NPTS];
    __shared__ float swv[2][16];
    __shared__ int swi[2][16];
    int b = blockIdx.x;
    int tid = threadIdx.x;
    const float* cb = coor + b * 3 * NPTS;
    float X[8], Y[8], Z[8], D[8];
    int n0 = tid * 8;
#pragma unroll
    for (int j = 0; j < 8; ++j) {
        float x = cb[n0 + j], y = cb[NPTS + n0 + j], z = cb[2 * NPTS + n0 + j];
        sx[n0 + j] = x; sy[n0 + j] = y; sz[n0 + j] = z;
        X[j] = x; Y[j] = y; Z[j] = z;
        D[j] = 1e10f;
    }
    __syncthreads();
    if (tid == 0) {
        fpsIdx[b * SPTS] = 0;
        float* oc = outCoor + b * 3 * SPTS;
        oc[0] = sx[0]; oc[SPTS] = sy[0]; oc[2 * SPTS] = sz[0];
    }
    int far = 0;
    int w = tid >> 6, lane = tid & 63;
    for (int t = 1; t < SPTS; ++t) {
        float fx = sx[far], fy = sy[far], fz = sz[far];
        // exact np-fp32 order: ((dx*dx + dy*dy) + dz*dz), no fma contraction
#pragma unroll
        for (int j = 0; j < 8; ++j) {
            float dx = __fsub_rn(X[j], fx);
            float dy = __fsub_rn(Y[j], fy);
            float dz = __fsub_rn(Z[j], fz);
            float d = __fadd_rn(__fadd_rn(__fmul_rn(dx, dx), __fmul_rn(dy, dy)),
                                __fmul_rn(dz, dz));
            D[j] = fminf(D[j], d);
        }
        float m = D[0];
        int id8 = 0;
#pragma unroll
        for (int j = 1; j < 8; ++j) {  // strict > keeps first occurrence
            bool g = D[j] > m;
            m = g ? D[j] : m;
            id8 = g ? j : id8;
        }
        float wm = m;
#pragma unroll
        for (int off = 32; off > 0; off >>= 1) wm = fmaxf(wm, __shfl_xor(wm, off));
        u64 bal = __ballot(m == wm);
        int src = __ffsll((unsigned long long)bal) - 1;  // lowest lane = lowest index
        int gsel = __shfl(n0 + id8, src);
        int p = t & 1;
        if (lane == 0) { swv[p][w] = wm; swi[p][w] = gsel; }
        __syncthreads();
        float v = swv[p][lane & 15];
        int gi = swi[p][lane & 15];
#pragma unroll
        for (int off = 8; off > 0; off >>= 1) {
            float ov = __shfl_xor(v, off);
            int og = __shfl_xor(gi, off);
            bool take = (ov > v) || (ov == v && og < gi);
            v = take ? ov : v;
            gi = take ? og : gi;
        }
        far = gi;
        if (tid == 0) {
            fpsIdx[b * SPTS + t] = gi;
            float* oc = outCoor + b * 3 * SPTS + t;
            oc[0] = sx[gi]; oc[SPTS] = sy[gi]; oc[2 * SPTS] = sz[gi];
        }
    }
}

// ---------------- grouping (exact f32, GEMM-style FMA dot): 1 wave/row ----------------
__global__ __launch_bounds__(256) void kgroup(const float* __restrict__ coor,
                                              const float* __restrict__ pp,
                                              const int* __restrict__ fpsIdx,
                                              int* __restrict__ gidxOut) {
    __shared__ u64 buf[4][256];
    __shared__ int cnt[4];
    int tid = threadIdx.x;
    int wv = tid >> 6, lane = tid & 63;
    if (tid < 4) cnt[tid] = 0;
    __syncthreads();
    int row = blockIdx.x * 4 + wv;
    int b = row >> 11, s = row & 2047;
    const float* cb = coor + b * 3 * NPTS;
    int n0 = fpsIdx[b * SPTS + s];
    float cx = cb[n0], cy = cb[NPTS + n0], cz = cb[2 * NPTS + n0];
    // cc from np.sum: forward LTR mul+add
    float cc = __fadd_rn(__fadd_rn(__fmul_rn(cx, cx), __fmul_rn(cy, cy)),
                         __fmul_rn(cz, cz));
    const float* ppb = pp + b * NPTS;
    u64 mk = ~0ull;
    for (int n = lane; n < NPTS; n += 64) {
        float x = cb[n], y = cb[NPTS + n], z = cb[2 * NPTS + n];
        // BLAS/Eigen k-loop: acc = fma(a_k,b_k,acc) ascending from 0;
        // step0 fma(x,cx,0) == rn(x*cx)
        float dot = __fmaf_rn(cz, z, __fmaf_rn(cy, y, __fmul_rn(cx, x)));
        float sq = __fsub_rn(__fadd_rn(cc, ppb[n]), __fmul_rn(2.0f, dot));
        // monotone float->uint map (tiny negative sq from cancellation ok)
        unsigned ub = __float_as_uint(sq);
        ub ^= (ub >> 31) ? 0xFFFFFFFFu : 0x80000000u;
        u64 key = ((u64)ub << 32) | (unsigned)n;
        mk = umin64(mk, key);
        if (sq <= 0.01f) {  // == NOT(d > 0.1**2): no f32 value between thresholds
            int p = atomicAdd(&cnt[wv], 1);
            if (p < 256) buf[wv][p] = key;
        }
    }
#pragma unroll
    for (int off = 32; off > 0; off >>= 1) mk = umin64(mk, __shfl_xor(mk, off));
    int C = cnt[wv];
    if (C > 256) C = 256;
    int* go = gidxOut + row * KN;
    if (C <= 32) {
        // kept set = all within-radius; pad with nearest (dups no-op under max)
        if (lane < 32) {
            unsigned idx = (lane < C) ? (unsigned)buf[wv][lane] : (unsigned)mk;
            go[lane] = (int)idx;
        }
    } else {
        u64 e[4];
#pragma unroll
        for (int i = 0; i < 4; ++i) {
            int j2 = lane + (i << 6);
            e[i] = (j2 < C) ? buf[wv][j2] : ~0ull;
        }
        int cl = 0;
        unsigned sel = 0;
        for (int it = 0; it < 32; ++it) {
            u64 lb = ~0ull;
            int li = 0;
#pragma unroll
            for (int i = 0; i < 4; ++i) {
                bool f = (((cl >> i) & 1) == 0) && (e[i] < lb);
                lb = f ? e[i] : lb;
                li = f ? i : li;
            }
            u64 wmin = lb;
#pragma unroll
            for (int off = 32; off > 0; off >>= 1) wmin = umin64(wmin, __shfl_xor(wmin, off));
            u64 bal = __ballot(lb == wmin);
            int src = __ffsll((unsigned long long)bal) - 1;
            if (lane == src) cl |= (1 << li);
            if (lane == it) sel = (unsigned)wmin;
        }
        if (lane < 32) go[lane] = (int)sel;
    }
}

// ---------------- MLP + BN + ReLU + maxpool: 1 block per (b,s) row ----------------
__global__ __launch_bounds__(256) void kfeat(const float* __restrict__ coor,
                                             const u16* __restrict__ feaT,
                                             const u16* __restrict__ Wpad,
                                             const float* __restrict__ bias,
                                             const float* __restrict__ gamma,
                                             const float* __restrict__ beta,
                                             const float* __restrict__ bmean,
                                             const float* __restrict__ bvar,
                                             const int* __restrict__ fpsIdx,
                                             const int* __restrict__ gidx,
                                             float* __restrict__ outFea) {
    __shared__ u16 g[KN][168];  // [neighbor][k]; row stride 336B (16B mult)
    int row = blockIdx.x;
    int b = row >> 11, s = row & 2047;
    int tid = threadIdx.x;
    {
        int k = tid >> 3, j = tid & 7;
        const float* cb = coor + b * 3 * NPTS;
        int nc = fpsIdx[b * SPTS + s];
        int nbr = gidx[row * KN + k];
        const uint4* f4 = (const uint4*)(feaT + (((size_t)b * NPTS + nbr) << 7));
        uint4* gr = (uint4*)&g[k][0];
        gr[j] = f4[j];
        gr[j + 8] = f4[j + 8];
        for (int c = 128 + j; c < CINP; c += 8) {
            u16 v = 0;
            if (c < 131) {
                int dim = c - 128;
                float pv = cb[dim * NPTS + nbr];
                float cv = cb[dim * NPTS + nc];
                v = f2b(__fdiv_rn(__fsub_rn(pv, cv), 0.1f));
            }
            g[k][c] = v;
        }
    }
    __syncthreads();
    int w = tid >> 6, lane = tid & 63;
    int mrow = lane & 15, q = lane >> 4;
    f32x4 acc[4][2] = {};
#pragma unroll
    for (int ks = 0; ks < 5; ++ks) {
        int kb = ks * 32 + q * 8;
        bf16x8 b0 = *(const bf16x8*)&g[mrow][kb];
        bf16x8 b1 = *(const bf16x8*)&g[mrow + 16][kb];
#pragma unroll
        for (int mt = 0; mt < 4; ++mt) {
            bf16x8 a = *(const bf16x8*)&Wpad[(size_t)(w * 64 + mt * 16 + mrow) * CINP + kb];
            acc[mt][0] = __builtin_amdgcn_mfma_f32_16x16x32_bf16(a, b0, acc[mt][0], 0, 0, 0);
            acc[mt][1] = __builtin_amdgcn_mfma_f32_16x16x32_bf16(a, b1, acc[mt][1], 0, 0, 0);
        }
    }
#pragma unroll
    for (int mt = 0; mt < 4; ++mt) {
#pragma unroll
        for (int r = 0; r < 4; ++r) {
            int m = w * 64 + mt * 16 + q * 4 + r;  // D row = q*4 + r, col = mrow
            float ga = gamma[m], be = beta[m];
            float mu = bmean[m], va = bvar[m], bi = bias[m];
            float rs = 1.0f / sqrtf(va + 1e-5f);
            float h0 = acc[mt][0][r] + bi;
            h0 = fmaxf(ga * (h0 - mu) * rs + be, 0.0f);
            float h1 = acc[mt][1][r] + bi;
            h1 = fmaxf(ga * (h1 - mu) * rs + be, 0.0f);
            float v = fmaxf(h0, h1);
#pragma unroll
            for (int off = 1; off < 16; off <<= 1) v = fmaxf(v, __shfl_xor(v, off));
            if (mrow == 0) outFea[((size_t)(b * 256 + m)) * SPTS + s] = v;
        }
    }
}

extern "C" void kernel_launch(void* const* d_in, const int* in_sizes, int n_in,
                              void* d_out, int out_size, void* d_ws, size_t ws_size,
                              hipStream_t stream) {
    const float* coor = (const float*)d_in[0];
    const float* fea = (const float*)d_in[1];
    const float* W = (const float*)d_in[2];
    const float* bias = (const float*)d_in[3];
    const float* gamma = (const float*)d_in[4];
    const float* beta = (const float*)d_in[5];
    const float* bmean = (const float*)d_in[6];
    const float* bvar = (const float*)d_in[7];
    char* ws = (char*)d_ws;
    int* fpsIdx = (int*)ws;                              // 32 KB
    int* gidx = (int*)(ws + 32768);                      // 1 MB
    float* pp = (float*)(ws + 32768 + 1048576);          // 128 KB
    u16* feaT = (u16*)(ws + 1212416);                    // 8 MB bf16
    u16* Wpad = (u16*)(ws + 9601024);                    // 80 KB bf16
    float* outC = (float*)d_out;                         // (B,3,S) f32
    float* outF = outC + NB * 3 * SPTS;                  // (B,2C,S) f32

    ktrans<<<256, 256, 0, stream>>>(fea, feaT);
    kmisc<<<288, 256, 0, stream>>>(coor, W, pp, Wpad);
    kfps<<<NB, 1024, 0, stream>>>(coor, fpsIdx, outC);
    kgroup<<<2048, 256, 0, stream>>>(coor, pp, fpsIdx, gidx);
    kfeat<<<8192, 256, 0, stream>>>(coor, feaT, Wpad, bias, gamma, beta, bmean, bvar,
                                    fpsIdx, gidx, outF);
}

// Round 6
// 2458.922 us; speedup vs baseline: 1.1109x; 1.1109x over previous
//
#include <hip/hip_runtime.h>
#include <stdint.h>

// SetAbstraction (PointNet++): B=4, N=8192, C=128, S=2048, K=32, R=0.1
// R5 PASSED (absmax 0.0156). Numerics locked:
//  - FPS: f32, d = ((dx*dx + dy*dy) + dz*dz) mul/add LTR (np.sum order)
//  - grouping: sq = (cc+pp) - 2*dot, dot = fma(cz,z, fma(cy,y, cx*x)) (BLAS)
//  - MLP: bf16 MFMA
// R6: kfps rewrite — spatial sort + exact wave-bbox skipping, DPP reductions,
// deferred global writes (no vmcnt(0) drain per iteration).

typedef unsigned short u16;
typedef unsigned long long u64;
typedef __bf16 bf16x8 __attribute__((ext_vector_type(8)));
typedef float f32x4 __attribute__((ext_vector_type(4)));

#define NB 4
#define NPTS 8192
#define CH 128
#define SPTS 2048
#define KN 32
#define CINP 160   // 131 padded to 160 (5 k-steps of 32)

__device__ __forceinline__ u16 f2b(float f) {  // f32 -> bf16 RNE
    unsigned x = __float_as_uint(f);
    unsigned r = (x + 0x7fffu + ((x >> 16) & 1u)) >> 16;
    return (u16)r;
}
__device__ __forceinline__ u64 umin64(u64 a, u64 b) { return a < b ? a : b; }

// (value-bits desc, pack asc) lexicographic max via DPP. Non-negative f32
// bits compare == float compare. old=self => invalid lanes no-op.
template <int CTRL>
__device__ __forceinline__ void dpp_take(unsigned& vb, unsigned& pk) {
    unsigned mv = (unsigned)__builtin_amdgcn_update_dpp((int)vb, (int)vb, CTRL, 0xF, 0xF, false);
    unsigned mp = (unsigned)__builtin_amdgcn_update_dpp((int)pk, (int)pk, CTRL, 0xF, 0xF, false);
    bool take = (mv > vb) || (mv == vb && mp < pk);
    vb = take ? mv : vb;
    pk = take ? mp : pk;
}

// ---------------- transpose fea (B,C,N) f32 -> feaT (B,N,C) bf16 ----------------
__global__ __launch_bounds__(256) void ktrans(const float* __restrict__ fea,
                                              u16* __restrict__ feaT) {
    __shared__ u16 T[128][130];
    int blk = blockIdx.x;  // 4 b x 64 n-tiles
    int b = blk >> 6, nt = blk & 63;
    int n0 = nt * 128;
    int t = threadIdx.x;
#pragma unroll 4
    for (int it = 0; it < 64; ++it) {
        int idx = it * 256 + t;
        int c = idx >> 7, nl = idx & 127;
        T[nl][c] = f2b(fea[((size_t)(b * CH + c)) * NPTS + n0 + nl]);
    }
    __syncthreads();
#pragma unroll 4
    for (int it = 0; it < 64; ++it) {
        int idx = it * 256 + t;
        int nl = idx >> 7, c = idx & 127;
        feaT[((size_t)(b * NPTS + n0 + nl)) * CH + c] = T[nl][c];
    }
}

// ---------------- pp = |p|^2 (np.sum LTR), W pad to bf16 ----------------
__global__ __launch_bounds__(256) void kmisc(const float* __restrict__ coor,
                                             const float* __restrict__ W,
                                             float* __restrict__ pp,
                                             u16* __restrict__ Wpad) {
    int gid = blockIdx.x * 256 + threadIdx.x;
    if (blockIdx.x < 128) {
        int n = gid & 8191, b = gid >> 13;
        const float* cb = coor + b * 3 * NPTS;
        float x = cb[n], y = cb[NPTS + n], z = cb[2 * NPTS + n];
        pp[gid] = __fadd_rn(__fadd_rn(__fmul_rn(x, x), __fmul_rn(y, y)),
                            __fmul_rn(z, z));
    } else {
        int i = gid - 128 * 256;
        if (i < 256 * CINP) {
            int d = i / CINP, k = i - d * CINP;
            Wpad[i] = (k < 131) ? f2b(W[d * 131 + k]) : (u16)0;
        }
    }
}

// ---------------- spatial counting sort into 16 xy-bins (per batch) ----------------
// Order within a bin is atomic-nondeterministic; FPS result is invariant
// (selection is by (D, origIdx), skips are exact no-ops).
__global__ __launch_bounds__(256) void ksort(const float* __restrict__ coor,
                                             float* __restrict__ sxg,
                                             float* __restrict__ syg,
                                             float* __restrict__ szg,
                                             int* __restrict__ sog) {
    __shared__ int hist[16], base[16];
    int b = blockIdx.x, tid = threadIdx.x;
    const float* cb = coor + b * 3 * NPTS;
    if (tid < 16) hist[tid] = 0;
    __syncthreads();
    int bins[32];
#pragma unroll 4
    for (int i = 0; i < 32; ++i) {
        int n = tid * 32 + i;
        float x = cb[n], y = cb[NPTS + n];
        int bx = min(3, (int)(x * 4.0f));
        int by = min(3, (int)(y * 4.0f));
        int bin = by * 4 + bx;
        bins[i] = bin;
        atomicAdd(&hist[bin], 1);
    }
    __syncthreads();
    if (tid == 0) {
        int acc = 0;
        for (int k2 = 0; k2 < 16; ++k2) { base[k2] = acc; acc += hist[k2]; hist[k2] = 0; }
    }
    __syncthreads();
#pragma unroll 4
    for (int i = 0; i < 32; ++i) {
        int n = tid * 32 + i;
        int bin = bins[i];
        int pos = base[bin] + atomicAdd(&hist[bin], 1);
        sxg[b * NPTS + pos] = cb[n];
        syg[b * NPTS + pos] = cb[NPTS + n];
        szg[b * NPTS + pos] = cb[2 * NPTS + n];
        sog[b * NPTS + pos] = n;
    }
}

// ---------------- FPS v2: 1 block (1024 thr) per batch ----------------
__global__ __launch_bounds__(1024) void kfps(const float* __restrict__ sxg,
                                             const float* __restrict__ syg,
                                             const float* __restrict__ szg,
                                             const int* __restrict__ sog,
                                             int* __restrict__ fpsIdx,
                                             float* __restrict__ outCoor) {
    __shared__ float sx[NPTS], sy[NPTS], sz[NPTS];
    __shared__ unsigned sWin[SPTS];
    __shared__ unsigned swv[2][16], swi[2][16];
    __shared__ int slot0s;
    int b = blockIdx.x, tid = threadIdx.x;
    int w = tid >> 6, lane = tid & 63;
    const float* gx = sxg + b * NPTS;
    const float* gy = syg + b * NPTS;
    const float* gz = szg + b * NPTS;
    const int* go = sog + b * NPTS;
    float X[8], Y[8], Z[8], D[8];
    unsigned PK[8];
    int n0 = tid * 8;
#pragma unroll
    for (int j = 0; j < 8; ++j) {
        float x = gx[n0 + j], y = gy[n0 + j], z = gz[n0 + j];
        sx[n0 + j] = x; sy[n0 + j] = y; sz[n0 + j] = z;
        X[j] = x; Y[j] = y; Z[j] = z;
        D[j] = 1e10f;
        int oi = go[n0 + j];
        PK[j] = ((unsigned)oi << 16) | (unsigned)(n0 + j);
        if (oi == 0) slot0s = n0 + j;
    }
    // wave bbox (init only; exactness irrelevant — used conservatively)
    float lox = X[0], hix = X[0], loy = Y[0], hiy = Y[0], loz = Z[0], hiz = Z[0];
#pragma unroll
    for (int j = 1; j < 8; ++j) {
        lox = fminf(lox, X[j]); hix = fmaxf(hix, X[j]);
        loy = fminf(loy, Y[j]); hiy = fmaxf(hiy, Y[j]);
        loz = fminf(loz, Z[j]); hiz = fmaxf(hiz, Z[j]);
    }
#pragma unroll
    for (int off = 32; off > 0; off >>= 1) {
        lox = fminf(lox, __shfl_xor(lox, off)); hix = fmaxf(hix, __shfl_xor(hix, off));
        loy = fminf(loy, __shfl_xor(loy, off)); hiy = fmaxf(hiy, __shfl_xor(hiy, off));
        loz = fminf(loz, __shfl_xor(loz, off)); hiz = fmaxf(hiz, __shfl_xor(hiz, off));
    }
    __syncthreads();
    if (tid == 0) sWin[0] = (unsigned)slot0s;  // origIdx 0 in high bits == 0
    int far = slot0s;
    float wMaxF = 3.4e38f;        // force active on first iteration
    unsigned cachedVB = 0, cachedPK = 0;
    for (int t = 1; t < SPTS; ++t) {
        float fx = sx[far], fy = sy[far], fz = sz[far];
        // exact-no-op skip test: min dist from c to wave bbox vs cached max D
        float ddx = fmaxf(0.0f, fmaxf(lox - fx, fx - hix));
        float ddy = fmaxf(0.0f, fmaxf(loy - fy, fy - hiy));
        float ddz = fmaxf(0.0f, fmaxf(loz - fz, fz - hiz));
        float dmin2 = ddx * ddx + ddy * ddy + ddz * ddz;
        unsigned wv_, wi_;
        if (dmin2 * 0.9995f >= wMaxF) {  // wave-uniform branch
            wv_ = cachedVB; wi_ = cachedPK;
        } else {
            // exact np-fp32 order: ((dx*dx + dy*dy) + dz*dz), no fma
#pragma unroll
            for (int j = 0; j < 8; ++j) {
                float dx = __fsub_rn(X[j], fx);
                float dy = __fsub_rn(Y[j], fy);
                float dz = __fsub_rn(Z[j], fz);
                float d = __fadd_rn(__fadd_rn(__fmul_rn(dx, dx), __fmul_rn(dy, dy)),
                                    __fmul_rn(dz, dz));
                D[j] = fminf(D[j], d);
            }
            unsigned mb = __float_as_uint(D[0]), mp = PK[0];
#pragma unroll
            for (int j = 1; j < 8; ++j) {
                unsigned db = __float_as_uint(D[j]);
                bool g = (db > mb) || (db == mb && PK[j] < mp);
                mb = g ? db : mb;
                mp = g ? PK[j] : mp;
            }
            // wave64 (val,pack) max-reduce: 4 butterflies + 2 row_bcast -> lane 63
            dpp_take<0xB1>(mb, mp);    // quad_perm xor1
            dpp_take<0x4E>(mb, mp);    // quad_perm xor2
            dpp_take<0x141>(mb, mp);   // row_half_mirror
            dpp_take<0x140>(mb, mp);   // row_mirror
            dpp_take<0x142>(mb, mp);   // row_bcast:15
            dpp_take<0x143>(mb, mp);   // row_bcast:31
            wv_ = (unsigned)__builtin_amdgcn_readlane((int)mb, 63);
            wi_ = (unsigned)__builtin_amdgcn_readlane((int)mp, 63);
            cachedVB = wv_; cachedPK = wi_;
            wMaxF = __uint_as_float(wv_);
        }
        int p = t & 1;
        if (lane == 0) { swv[p][w] = wv_; swi[p][w] = wi_; }
        __syncthreads();
        unsigned v2 = swv[p][lane & 15], i2 = swi[p][lane & 15];
        dpp_take<0xB1>(v2, i2);
        dpp_take<0x4E>(v2, i2);
        dpp_take<0x141>(v2, i2);
        dpp_take<0x140>(v2, i2);   // all lanes now hold the global winner
        far = (int)(i2 & 0xFFFFu);
        if (tid == 0) sWin[t] = i2;
    }
    __syncthreads();
    // deferred flush: fpsIdx (original indices) + gathered coords
    for (int i = tid; i < SPTS; i += 1024) {
        unsigned pk = sWin[i];
        int slot = (int)(pk & 0xFFFFu);
        fpsIdx[b * SPTS + i] = (int)(pk >> 16);
        float* oc = outCoor + b * 3 * SPTS + i;
        oc[0] = sx[slot]; oc[SPTS] = sy[slot]; oc[2 * SPTS] = sz[slot];
    }
}

// ---------------- grouping (exact f32, GEMM-style FMA dot): 1 wave/row ----------------
__global__ __launch_bounds__(256) void kgroup(const float* __restrict__ coor,
                                              const float* __restrict__ pp,
                                              const int* __restrict__ fpsIdx,
                                              int* __restrict__ gidxOut) {
    __shared__ u64 buf[4][256];
    __shared__ int cnt[4];
    int tid = threadIdx.x;
    int wv = tid >> 6, lane = tid & 63;
    if (tid < 4) cnt[tid] = 0;
    __syncthreads();
    int row = blockIdx.x * 4 + wv;
    int b = row >> 11, s = row & 2047;
    const float* cb = coor + b * 3 * NPTS;
    int n0 = fpsIdx[b * SPTS + s];
    float cx = cb[n0], cy = cb[NPTS + n0], cz = cb[2 * NPTS + n0];
    float cc = __fadd_rn(__fadd_rn(__fmul_rn(cx, cx), __fmul_rn(cy, cy)),
                         __fmul_rn(cz, cz));
    const float* ppb = pp + b * NPTS;
    u64 mk = ~0ull;
    for (int n = lane; n < NPTS; n += 64) {
        float x = cb[n], y = cb[NPTS + n], z = cb[2 * NPTS + n];
        float dot = __fmaf_rn(cz, z, __fmaf_rn(cy, y, __fmul_rn(cx, x)));
        float sq = __fsub_rn(__fadd_rn(cc, ppb[n]), __fmul_rn(2.0f, dot));
        unsigned ub = __float_as_uint(sq);
        ub ^= (ub >> 31) ? 0xFFFFFFFFu : 0x80000000u;
        u64 key = ((u64)ub << 32) | (unsigned)n;
        mk = umin64(mk, key);
        if (sq <= 0.01f) {
            int p = atomicAdd(&cnt[wv], 1);
            if (p < 256) buf[wv][p] = key;
        }
    }
#pragma unroll
    for (int off = 32; off > 0; off >>= 1) mk = umin64(mk, __shfl_xor(mk, off));
    int C = cnt[wv];
    if (C > 256) C = 256;
    int* go = gidxOut + row * KN;
    if (C <= 32) {
        if (lane < 32) {
            unsigned idx = (lane < C) ? (unsigned)buf[wv][lane] : (unsigned)mk;
            go[lane] = (int)idx;
        }
    } else {
        u64 e[4];
#pragma unroll
        for (int i = 0; i < 4; ++i) {
            int j2 = lane + (i << 6);
            e[i] = (j2 < C) ? buf[wv][j2] : ~0ull;
        }
        int cl = 0;
        unsigned sel = 0;
        for (int it = 0; it < 32; ++it) {
            u64 lb = ~0ull;
            int li = 0;
#pragma unroll
            for (int i = 0; i < 4; ++i) {
                bool f = (((cl >> i) & 1) == 0) && (e[i] < lb);
                lb = f ? e[i] : lb;
                li = f ? i : li;
            }
            u64 wmin = lb;
#pragma unroll
            for (int off = 32; off > 0; off >>= 1) wmin = umin64(wmin, __shfl_xor(wmin, off));
            u64 bal = __ballot(lb == wmin);
            int src = __ffsll((unsigned long long)bal) - 1;
            if (lane == src) cl |= (1 << li);
            if (lane == it) sel = (unsigned)wmin;
        }
        if (lane < 32) go[lane] = (int)sel;
    }
}

// ---------------- MLP + BN + ReLU + maxpool: 1 block per (b,s) row ----------------
__global__ __launch_bounds__(256) void kfeat(const float* __restrict__ coor,
                                             const u16* __restrict__ feaT,
                                             const u16* __restrict__ Wpad,
                                             const float* __restrict__ bias,
                                             const float* __restrict__ gamma,
                                             const float* __restrict__ beta,
                                             const float* __restrict__ bmean,
                                             const float* __restrict__ bvar,
                                             const int* __restrict__ fpsIdx,
                                             const int* __restrict__ gidx,
                                             float* __restrict__ outFea) {
    __shared__ u16 g[KN][168];
    int row = blockIdx.x;
    int b = row >> 11, s = row & 2047;
    int tid = threadIdx.x;
    {
        int k = tid >> 3, j = tid & 7;
        const float* cb = coor + b * 3 * NPTS;
        int nc = fpsIdx[b * SPTS + s];
        int nbr = gidx[row * KN + k];
        const uint4* f4 = (const uint4*)(feaT + (((size_t)b * NPTS + nbr) << 7));
        uint4* gr = (uint4*)&g[k][0];
        gr[j] = f4[j];
        gr[j + 8] = f4[j + 8];
        for (int c = 128 + j; c < CINP; c += 8) {
            u16 v = 0;
            if (c < 131) {
                int dim = c - 128;
                float pv = cb[dim * NPTS + nbr];
                float cv = cb[dim * NPTS + nc];
                v = f2b(__fdiv_rn(__fsub_rn(pv, cv), 0.1f));
            }
            g[k][c] = v;
        }
    }
    __syncthreads();
    int w = tid >> 6, lane = tid & 63;
    int mrow = lane & 15, q = lane >> 4;
    f32x4 acc[4][2] = {};
#pragma unroll
    for (int ks = 0; ks < 5; ++ks) {
        int kb = ks * 32 + q * 8;
        bf16x8 b0 = *(const bf16x8*)&g[mrow][kb];
        bf16x8 b1 = *(const bf16x8*)&g[mrow + 16][kb];
#pragma unroll
        for (int mt = 0; mt < 4; ++mt) {
            bf16x8 a = *(const bf16x8*)&Wpad[(size_t)(w * 64 + mt * 16 + mrow) * CINP + kb];
            acc[mt][0] = __builtin_amdgcn_mfma_f32_16x16x32_bf16(a, b0, acc[mt][0], 0, 0, 0);
            acc[mt][1] = __builtin_amdgcn_mfma_f32_16x16x32_bf16(a, b1, acc[mt][1], 0, 0, 0);
        }
    }
#pragma unroll
    for (int mt = 0; mt < 4; ++mt) {
#pragma unroll
        for (int r = 0; r < 4; ++r) {
            int m = w * 64 + mt * 16 + q * 4 + r;
            float ga = gamma[m], be = beta[m];
            float mu = bmean[m], va = bvar[m], bi = bias[m];
            float rs = 1.0f / sqrtf(va + 1e-5f);
            float h0 = acc[mt][0][r] + bi;
            h0 = fmaxf(ga * (h0 - mu) * rs + be, 0.0f);
            float h1 = acc[mt][1][r] + bi;
            h1 = fmaxf(ga * (h1 - mu) * rs + be, 0.0f);
            float v = fmaxf(h0, h1);
#pragma unroll
            for (int off = 1; off < 16; off <<= 1) v = fmaxf(v, __shfl_xor(v, off));
            if (mrow == 0) outFea[((size_t)(b * 256 + m)) * SPTS + s] = v;
        }
    }
}

extern "C" void kernel_launch(void* const* d_in, const int* in_sizes, int n_in,
                              void* d_out, int out_size, void* d_ws, size_t ws_size,
                              hipStream_t stream) {
    const float* coor = (const float*)d_in[0];
    const float* fea = (const float*)d_in[1];
    const float* W = (const float*)d_in[2];
    const float* bias = (const float*)d_in[3];
    const float* gamma = (const float*)d_in[4];
    const float* beta = (const float*)d_in[5];
    const float* bmean = (const float*)d_in[6];
    const float* bvar = (const float*)d_in[7];
    char* ws = (char*)d_ws;
    int* fpsIdx = (int*)ws;                              // 32 KB
    int* gidx = (int*)(ws + 32768);                      // 1 MB
    float* pp = (float*)(ws + 32768 + 1048576);          // 128 KB
    u16* feaT = (u16*)(ws + 1212416);                    // 8 MB bf16
    u16* Wpad = (u16*)(ws + 9601024);                    // 80 KB bf16
    float* sxg = (float*)(ws + 9682944);                 // 128 KB
    float* syg = (float*)(ws + 9814016);                 // 128 KB
    float* szg = (float*)(ws + 9945088);                 // 128 KB
    int* sog = (int*)(ws + 10076160);                    // 128 KB
    float* outC = (float*)d_out;                         // (B,3,S) f32
    float* outF = outC + NB * 3 * SPTS;                  // (B,2C,S) f32

    ktrans<<<256, 256, 0, stream>>>(fea, feaT);
    kmisc<<<288, 256, 0, stream>>>(coor, W, pp, Wpad);
    ksort<<<NB, 256, 0, stream>>>(coor, sxg, syg, szg, sog);
    kfps<<<NB, 1024, 0, stream>>>(sxg, syg, szg, sog, fpsIdx, outC);
    kgroup<<<2048, 256, 0, stream>>>(coor, pp, fpsIdx, gidx);
    kfeat<<<8192, 256, 0, stream>>>(coor, feaT, Wpad, bias, gamma, beta, bmean, bvar,
                                    fpsIdx, gidx, outF);
}

// Round 7
// 1949.477 us; speedup vs baseline: 1.4012x; 1.2613x over previous
//
#include <hip/hip_runtime.h>
#include <stdint.h>

// SetAbstraction (PointNet++): B=4, N=8192, C=128, S=2048, K=32, R=0.1
// Numerics locked (R5 passed, absmax 0.0156):
//  - FPS: f32, d = ((dx*dx + dy*dy) + dz*dz) mul/add LTR (np.sum order)
//  - grouping: sq = (cc+pp) - 2*dot, dot = fma(cz,z, fma(cy,y, cx*x)) (BLAS)
//  - MLP: bf16 MFMA
// R7: kfps is VALU-issue-bound (R6: 64% VALU on active CUs). Cut insts:
// u64-packed (Dbits<<32|~PK) keys for all reduces, 7-fmax tree + tie-select
// thread argmax, float4 LDS points (1 ds_read_b128 broadcast).

typedef unsigned short u16;
typedef unsigned long long u64;
typedef __bf16 bf16x8 __attribute__((ext_vector_type(8)));
typedef float f32x4 __attribute__((ext_vector_type(4)));

#define NB 4
#define NPTS 8192
#define CH 128
#define SPTS 2048
#define KN 32
#define CINP 160   // 131 padded to 160 (5 k-steps of 32)

__device__ __forceinline__ u16 f2b(float f) {  // f32 -> bf16 RNE
    unsigned x = __float_as_uint(f);
    unsigned r = (x + 0x7fffu + ((x >> 16) & 1u)) >> 16;
    return (u16)r;
}
__device__ __forceinline__ u64 umin64(u64 a, u64 b) { return a < b ? a : b; }

// one DPP max step on a u64 key (hi=value bits, lo=~pk). Lane-permute applied
// to both halves identically keeps (hi,lo) paired. bound_ctrl=false: invalid
// lanes return old (=self) -> no-op compare.
template <int CTRL>
__device__ __forceinline__ u64 dpp_max64(u64 k) {
    unsigned lo = (unsigned)k, hi = (unsigned)(k >> 32);
    unsigned mlo = (unsigned)__builtin_amdgcn_update_dpp((int)lo, (int)lo, CTRL, 0xF, 0xF, false);
    unsigned mhi = (unsigned)__builtin_amdgcn_update_dpp((int)hi, (int)hi, CTRL, 0xF, 0xF, false);
    u64 m = ((u64)mhi << 32) | mlo;
    return m > k ? m : k;
}

// ---------------- transpose fea (B,C,N) f32 -> feaT (B,N,C) bf16 ----------------
__global__ __launch_bounds__(256) void ktrans(const float* __restrict__ fea,
                                              u16* __restrict__ feaT) {
    __shared__ u16 T[128][130];
    int blk = blockIdx.x;  // 4 b x 64 n-tiles
    int b = blk >> 6, nt = blk & 63;
    int n0 = nt * 128;
    int t = threadIdx.x;
#pragma unroll 4
    for (int it = 0; it < 64; ++it) {
        int idx = it * 256 + t;
        int c = idx >> 7, nl = idx & 127;
        T[nl][c] = f2b(fea[((size_t)(b * CH + c)) * NPTS + n0 + nl]);
    }
    __syncthreads();
#pragma unroll 4
    for (int it = 0; it < 64; ++it) {
        int idx = it * 256 + t;
        int nl = idx >> 7, c = idx & 127;
        feaT[((size_t)(b * NPTS + n0 + nl)) * CH + c] = T[nl][c];
    }
}

// ---------------- pp = |p|^2 (np.sum LTR), W pad to bf16 ----------------
__global__ __launch_bounds__(256) void kmisc(const float* __restrict__ coor,
                                             const float* __restrict__ W,
                                             float* __restrict__ pp,
                                             u16* __restrict__ Wpad) {
    int gid = blockIdx.x * 256 + threadIdx.x;
    if (blockIdx.x < 128) {
        int n = gid & 8191, b = gid >> 13;
        const float* cb = coor + b * 3 * NPTS;
        float x = cb[n], y = cb[NPTS + n], z = cb[2 * NPTS + n];
        pp[gid] = __fadd_rn(__fadd_rn(__fmul_rn(x, x), __fmul_rn(y, y)),
                            __fmul_rn(z, z));
    } else {
        int i = gid - 128 * 256;
        if (i < 256 * CINP) {
            int d = i / CINP, k = i - d * CINP;
            Wpad[i] = (k < 131) ? f2b(W[d * 131 + k]) : (u16)0;
        }
    }
}

// ---------------- spatial counting sort into 16 xy-bins (per batch) ----------------
__global__ __launch_bounds__(256) void ksort(const float* __restrict__ coor,
                                             float* __restrict__ sxg,
                                             float* __restrict__ syg,
                                             float* __restrict__ szg,
                                             int* __restrict__ sog) {
    __shared__ int hist[16], base[16];
    int b = blockIdx.x, tid = threadIdx.x;
    const float* cb = coor + b * 3 * NPTS;
    if (tid < 16) hist[tid] = 0;
    __syncthreads();
    int bins[32];
#pragma unroll 4
    for (int i = 0; i < 32; ++i) {
        int n = tid * 32 + i;
        float x = cb[n], y = cb[NPTS + n];
        int bx = min(3, (int)(x * 4.0f));
        int by = min(3, (int)(y * 4.0f));
        int bin = by * 4 + bx;
        bins[i] = bin;
        atomicAdd(&hist[bin], 1);
    }
    __syncthreads();
    if (tid == 0) {
        int acc = 0;
        for (int k2 = 0; k2 < 16; ++k2) { base[k2] = acc; acc += hist[k2]; hist[k2] = 0; }
    }
    __syncthreads();
#pragma unroll 4
    for (int i = 0; i < 32; ++i) {
        int n = tid * 32 + i;
        int bin = bins[i];
        int pos = base[bin] + atomicAdd(&hist[bin], 1);
        sxg[b * NPTS + pos] = cb[n];
        syg[b * NPTS + pos] = cb[NPTS + n];
        szg[b * NPTS + pos] = cb[2 * NPTS + n];
        sog[b * NPTS + pos] = n;
    }
}

// ---------------- FPS v3: 1 block (1024 thr) per batch, u64 keys ----------------
__global__ __launch_bounds__(1024) void kfps(const float* __restrict__ sxg,
                                             const float* __restrict__ syg,
                                             const float* __restrict__ szg,
                                             const int* __restrict__ sog,
                                             int* __restrict__ fpsIdx,
                                             float* __restrict__ outCoor) {
    __shared__ float4 sp[NPTS];          // 128 KB
    __shared__ unsigned sWin[SPTS];      // 8 KB
    __shared__ u64 sKey[2][16];
    __shared__ int slot0s;
    int tid = threadIdx.x;
    int b = blockIdx.x;
    int w = tid >> 6, lane = tid & 63;
    const float* gx = sxg + b * NPTS;
    const float* gy = syg + b * NPTS;
    const float* gz = szg + b * NPTS;
    const int* go = sog + b * NPTS;
    float X[8], Y[8], Z[8], D[8];
    unsigned PK[8];
    int n0 = tid * 8;
#pragma unroll
    for (int j = 0; j < 8; ++j) {
        float x = gx[n0 + j], y = gy[n0 + j], z = gz[n0 + j];
        sp[n0 + j] = make_float4(x, y, z, 0.0f);
        X[j] = x; Y[j] = y; Z[j] = z;
        D[j] = 1e10f;
        int oi = go[n0 + j];
        PK[j] = ((unsigned)oi << 16) | (unsigned)(n0 + j);
        if (oi == 0) slot0s = n0 + j;
    }
    // wave bbox (used conservatively; exactness irrelevant)
    float lox = X[0], hix = X[0], loy = Y[0], hiy = Y[0], loz = Z[0], hiz = Z[0];
#pragma unroll
    for (int j = 1; j < 8; ++j) {
        lox = fminf(lox, X[j]); hix = fmaxf(hix, X[j]);
        loy = fminf(loy, Y[j]); hiy = fmaxf(hiy, Y[j]);
        loz = fminf(loz, Z[j]); hiz = fmaxf(hiz, Z[j]);
    }
#pragma unroll
    for (int off = 32; off > 0; off >>= 1) {
        lox = fminf(lox, __shfl_xor(lox, off)); hix = fmaxf(hix, __shfl_xor(hix, off));
        loy = fminf(loy, __shfl_xor(loy, off)); hiy = fmaxf(hiy, __shfl_xor(hiy, off));
        loz = fminf(loz, __shfl_xor(loz, off)); hiz = fmaxf(hiz, __shfl_xor(hiz, off));
    }
    __syncthreads();
    int far = slot0s;
    if (tid == 0) sWin[0] = (unsigned)slot0s;  // origIdx 0 in high bits
    float wMaxF = 3.4e38f;  // force update on first iteration
    u64 cachedKey = 0;
    for (int t = 1; t < SPTS; ++t) {
        float4 c = sp[far];  // uniform addr -> broadcast ds_read_b128
        float fx = c.x, fy = c.y, fz = c.z;
        // exact-no-op skip: min dist(c, wave bbox)^2 vs max D at last update
        float ddx = fmaxf(0.0f, fmaxf(lox - fx, fx - hix));
        float ddy = fmaxf(0.0f, fmaxf(loy - fy, fy - hiy));
        float ddz = fmaxf(0.0f, fmaxf(loz - fz, fz - hiz));
        float dmin2 = ddx * ddx + ddy * ddy + ddz * ddz;
        if (!(dmin2 * 0.9995f >= wMaxF)) {  // wave-uniform branch
            // exact np-fp32 order: ((dx*dx + dy*dy) + dz*dz), no fma
#pragma unroll
            for (int j = 0; j < 8; ++j) {
                float dx = __fsub_rn(X[j], fx);
                float dy = __fsub_rn(Y[j], fy);
                float dz = __fsub_rn(Z[j], fz);
                float d = __fadd_rn(__fadd_rn(__fmul_rn(dx, dx), __fmul_rn(dy, dy)),
                                    __fmul_rn(dz, dz));
                D[j] = fminf(D[j], d);
            }
            // two-phase thread argmax: value tree, then min-PK among ties
            float m01 = fmaxf(D[0], D[1]), m23 = fmaxf(D[2], D[3]);
            float m45 = fmaxf(D[4], D[5]), m67 = fmaxf(D[6], D[7]);
            float m = fmaxf(fmaxf(m01, m23), fmaxf(m45, m67));
            unsigned sel = 0xFFFFFFFFu;
#pragma unroll
            for (int j = 0; j < 8; ++j)
                sel = (D[j] == m) ? (sel < PK[j] ? sel : PK[j]) : sel;
            u64 key = ((u64)__float_as_uint(m) << 32) | (unsigned)~sel;
            // wave64 max-reduce (6 DPP stages), winner at lane 63
            key = dpp_max64<0xB1>(key);    // quad_perm xor1
            key = dpp_max64<0x4E>(key);    // quad_perm xor2
            key = dpp_max64<0x141>(key);   // row_half_mirror
            key = dpp_max64<0x140>(key);   // row_mirror
            key = dpp_max64<0x142>(key);   // row_bcast:15
            key = dpp_max64<0x143>(key);   // row_bcast:31
            unsigned wlo = (unsigned)__builtin_amdgcn_readlane((int)(unsigned)key, 63);
            unsigned whi = (unsigned)__builtin_amdgcn_readlane((int)(unsigned)(key >> 32), 63);
            cachedKey = ((u64)whi << 32) | wlo;
            wMaxF = __uint_as_float(whi);
        }
        int p = t & 1;
        if (lane == 0) sKey[p][w] = cachedKey;
        __syncthreads();
        // all waves redundantly reduce the 16 per-wave keys
        u64 kk = sKey[p][lane & 15];
        kk = dpp_max64<0xB1>(kk);
        kk = dpp_max64<0x4E>(kk);
        kk = dpp_max64<0x141>(kk);
        kk = dpp_max64<0x140>(kk);   // all lanes hold the global winner
        unsigned pk = ~(unsigned)kk;
        far = (int)(pk & 0xFFFFu);
        if (tid == 0) sWin[t] = pk;
    }
    __syncthreads();
    // deferred flush
    for (int i = tid; i < SPTS; i += 1024) {
        unsigned pk = sWin[i];
        int slot = (int)(pk & 0xFFFFu);
        float4 c = sp[slot];
        fpsIdx[b * SPTS + i] = (int)(pk >> 16);
        float* oc = outCoor + b * 3 * SPTS + i;
        oc[0] = c.x; oc[SPTS] = c.y; oc[2 * SPTS] = c.z;
    }
}

// ---------------- grouping (exact f32, GEMM-style FMA dot): 1 wave/row ----------------
__global__ __launch_bounds__(256) void kgroup(const float* __restrict__ coor,
                                              const float* __restrict__ pp,
                                              const int* __restrict__ fpsIdx,
                                              int* __restrict__ gidxOut) {
    __shared__ u64 buf[4][256];
    __shared__ int cnt[4];
    int tid = threadIdx.x;
    int wv = tid >> 6, lane = tid & 63;
    if (tid < 4) cnt[tid] = 0;
    __syncthreads();
    int row = blockIdx.x * 4 + wv;
    int b = row >> 11, s = row & 2047;
    const float* cb = coor + b * 3 * NPTS;
    int n0 = fpsIdx[b * SPTS + s];
    float cx = cb[n0], cy = cb[NPTS + n0], cz = cb[2 * NPTS + n0];
    float cc = __fadd_rn(__fadd_rn(__fmul_rn(cx, cx), __fmul_rn(cy, cy)),
                         __fmul_rn(cz, cz));
    const float* ppb = pp + b * NPTS;
    u64 mk = ~0ull;
    for (int n = lane; n < NPTS; n += 64) {
        float x = cb[n], y = cb[NPTS + n], z = cb[2 * NPTS + n];
        float dot = __fmaf_rn(cz, z, __fmaf_rn(cy, y, __fmul_rn(cx, x)));
        float sq = __fsub_rn(__fadd_rn(cc, ppb[n]), __fmul_rn(2.0f, dot));
        unsigned ub = __float_as_uint(sq);
        ub ^= (ub >> 31) ? 0xFFFFFFFFu : 0x80000000u;
        u64 key = ((u64)ub << 32) | (unsigned)n;
        mk = umin64(mk, key);
        if (sq <= 0.01f) {
            int p = atomicAdd(&cnt[wv], 1);
            if (p < 256) buf[wv][p] = key;
        }
    }
#pragma unroll
    for (int off = 32; off > 0; off >>= 1) mk = umin64(mk, __shfl_xor(mk, off));
    int C = cnt[wv];
    if (C > 256) C = 256;
    int* go = gidxOut + row * KN;
    if (C <= 32) {
        if (lane < 32) {
            unsigned idx = (lane < C) ? (unsigned)buf[wv][lane] : (unsigned)mk;
            go[lane] = (int)idx;
        }
    } else {
        u64 e[4];
#pragma unroll
        for (int i = 0; i < 4; ++i) {
            int j2 = lane + (i << 6);
            e[i] = (j2 < C) ? buf[wv][j2] : ~0ull;
        }
        int cl = 0;
        unsigned sel = 0;
        for (int it = 0; it < 32; ++it) {
            u64 lb = ~0ull;
            int li = 0;
#pragma unroll
            for (int i = 0; i < 4; ++i) {
                bool f = (((cl >> i) & 1) == 0) && (e[i] < lb);
                lb = f ? e[i] : lb;
                li = f ? i : li;
            }
            u64 wmin = lb;
#pragma unroll
            for (int off = 32; off > 0; off >>= 1) wmin = umin64(wmin, __shfl_xor(wmin, off));
            u64 bal = __ballot(lb == wmin);
            int src = __ffsll((unsigned long long)bal) - 1;
            if (lane == src) cl |= (1 << li);
            if (lane == it) sel = (unsigned)wmin;
        }
        if (lane < 32) go[lane] = (int)sel;
    }
}

// ---------------- MLP + BN + ReLU + maxpool: 1 block per (b,s) row ----------------
__global__ __launch_bounds__(256) void kfeat(const float* __restrict__ coor,
                                             const u16* __restrict__ feaT,
                                             const u16* __restrict__ Wpad,
                                             const float* __restrict__ bias,
                                             const float* __restrict__ gamma,
                                             const float* __restrict__ beta,
                                             const float* __restrict__ bmean,
                                             const float* __restrict__ bvar,
                                             const int* __restrict__ fpsIdx,
                                             const int* __restrict__ gidx,
                                             float* __restrict__ outFea) {
    __shared__ u16 g[KN][168];
    int row = blockIdx.x;
    int b = row >> 11, s = row & 2047;
    int tid = threadIdx.x;
    {
        int k = tid >> 3, j = tid & 7;
        const float* cb = coor + b * 3 * NPTS;
        int nc = fpsIdx[b * SPTS + s];
        int nbr = gidx[row * KN + k];
        const uint4* f4 = (const uint4*)(feaT + (((size_t)b * NPTS + nbr) << 7));
        uint4* gr = (uint4*)&g[k][0];
        gr[j] = f4[j];
        gr[j + 8] = f4[j + 8];
        for (int c = 128 + j; c < CINP; c += 8) {
            u16 v = 0;
            if (c < 131) {
                int dim = c - 128;
                float pv = cb[dim * NPTS + nbr];
                float cv = cb[dim * NPTS + nc];
                v = f2b(__fdiv_rn(__fsub_rn(pv, cv), 0.1f));
            }
            g[k][c] = v;
        }
    }
    __syncthreads();
    int w = tid >> 6, lane = tid & 63;
    int mrow = lane & 15, q = lane >> 4;
    f32x4 acc[4][2] = {};
#pragma unroll
    for (int ks = 0; ks < 5; ++ks) {
        int kb = ks * 32 + q * 8;
        bf16x8 b0 = *(const bf16x8*)&g[mrow][kb];
        bf16x8 b1 = *(const bf16x8*)&g[mrow + 16][kb];
#pragma unroll
        for (int mt = 0; mt < 4; ++mt) {
            bf16x8 a = *(const bf16x8*)&Wpad[(size_t)(w * 64 + mt * 16 + mrow) * CINP + kb];
            acc[mt][0] = __builtin_amdgcn_mfma_f32_16x16x32_bf16(a, b0, acc[mt][0], 0, 0, 0);
            acc[mt][1] = __builtin_amdgcn_mfma_f32_16x16x32_bf16(a, b1, acc[mt][1], 0, 0, 0);
        }
    }
#pragma unroll
    for (int mt = 0; mt < 4; ++mt) {
#pragma unroll
        for (int r = 0; r < 4; ++r) {
            int m = w * 64 + mt * 16 + q * 4 + r;
            float ga = gamma[m], be = beta[m];
            float mu = bmean[m], va = bvar[m], bi = bias[m];
            float rs = 1.0f / sqrtf(va + 1e-5f);
            float h0 = acc[mt][0][r] + bi;
            h0 = fmaxf(ga * (h0 - mu) * rs + be, 0.0f);
            float h1 = acc[mt][1][r] + bi;
            h1 = fmaxf(ga * (h1 - mu) * rs + be, 0.0f);
            float v = fmaxf(h0, h1);
#pragma unroll
            for (int off = 1; off < 16; off <<= 1) v = fmaxf(v, __shfl_xor(v, off));
            if (mrow == 0) outFea[((size_t)(b * 256 + m)) * SPTS + s] = v;
        }
    }
}

extern "C" void kernel_launch(void* const* d_in, const int* in_sizes, int n_in,
                              void* d_out, int out_size, void* d_ws, size_t ws_size,
                              hipStream_t stream) {
    const float* coor = (const float*)d_in[0];
    const float* fea = (const float*)d_in[1];
    const float* W = (const float*)d_in[2];
    const float* bias = (const float*)d_in[3];
    const float* gamma = (const float*)d_in[4];
    const float* beta = (const float*)d_in[5];
    const float* bmean = (const float*)d_in[6];
    const float* bvar = (const float*)d_in[7];
    char* ws = (char*)d_ws;
    int* fpsIdx = (int*)ws;                              // 32 KB
    int* gidx = (int*)(ws + 32768);                      // 1 MB
    float* pp = (float*)(ws + 32768 + 1048576);          // 128 KB
    u16* feaT = (u16*)(ws + 1212416);                    // 8 MB bf16
    u16* Wpad = (u16*)(ws + 9601024);                    // 80 KB bf16
    float* sxg = (float*)(ws + 9682944);                 // 128 KB
    float* syg = (float*)(ws + 9814016);                 // 128 KB
    float* szg = (float*)(ws + 9945088);                 // 128 KB
    int* sog = (int*)(ws + 10076160);                    // 128 KB
    float* outC = (float*)d_out;                         // (B,3,S) f32
    float* outF = outC + NB * 3 * SPTS;                  // (B,2C,S) f32

    ktrans<<<256, 256, 0, stream>>>(fea, feaT);
    kmisc<<<288, 256, 0, stream>>>(coor, W, pp, Wpad);
    ksort<<<NB, 256, 0, stream>>>(coor, sxg, syg, szg, sog);
    kfps<<<NB, 1024, 0, stream>>>(sxg, syg, szg, sog, fpsIdx, outC);
    kgroup<<<2048, 256, 0, stream>>>(coor, pp, fpsIdx, gidx);
    kfeat<<<8192, 256, 0, stream>>>(coor, feaT, Wpad, bias, gamma, beta, bmean, bvar,
                                    fpsIdx, gidx, outF);
}

// Round 8
// 1815.896 us; speedup vs baseline: 1.5043x; 1.0736x over previous
//
#include <hip/hip_runtime.h>
#include <stdint.h>

// SetAbstraction (PointNet++): B=4, N=8192, C=128, S=2048, K=32, R=0.1
// Numerics locked (R5 passed, absmax 0.0156):
//  - FPS: f32, d = ((dx*dx + dy*dy) + dz*dz) mul/add LTR (np.sum order)
//  - grouping: sq = (cc+pp) - 2*dot, dot = fma(cz,z, fma(cy,y, cx*x)) (BLAS)
//  - MLP: bf16 MFMA
// R8 kfps: LDS-atomic block combine (ds_max_u64, 4-slot rotation), packed-f32
// update (fp contract off => exact per-element RN), value-only DPP wave max
// with unique-winner fast path.

typedef unsigned short u16;
typedef unsigned long long u64;
typedef __bf16 bf16x8 __attribute__((ext_vector_type(8)));
typedef float f32x4 __attribute__((ext_vector_type(4)));
typedef float f32x2 __attribute__((ext_vector_type(2)));

#define NB 4
#define NPTS 8192
#define CH 128
#define SPTS 2048
#define KN 32
#define CINP 160   // 131 padded to 160 (5 k-steps of 32)

__device__ __forceinline__ u16 f2b(float f) {  // f32 -> bf16 RNE
    unsigned x = __float_as_uint(f);
    unsigned r = (x + 0x7fffu + ((x >> 16) & 1u)) >> 16;
    return (u16)r;
}
__device__ __forceinline__ u64 umin64(u64 a, u64 b) { return a < b ? a : b; }

template <int CTRL>
__device__ __forceinline__ u64 dpp_max64(u64 k) {
    unsigned lo = (unsigned)k, hi = (unsigned)(k >> 32);
    unsigned mlo = (unsigned)__builtin_amdgcn_update_dpp((int)lo, (int)lo, CTRL, 0xF, 0xF, false);
    unsigned mhi = (unsigned)__builtin_amdgcn_update_dpp((int)hi, (int)hi, CTRL, 0xF, 0xF, false);
    u64 m = ((u64)mhi << 32) | mlo;
    return m > k ? m : k;
}
// uint-bits max (== float max for non-negative floats)
template <int CTRL>
__device__ __forceinline__ unsigned dpp_maxu(unsigned v) {
    unsigned mv = (unsigned)__builtin_amdgcn_update_dpp((int)v, (int)v, CTRL, 0xF, 0xF, false);
    return mv > v ? mv : v;
}

// ---------------- transpose fea (B,C,N) f32 -> feaT (B,N,C) bf16 ----------------
__global__ __launch_bounds__(256) void ktrans(const float* __restrict__ fea,
                                              u16* __restrict__ feaT) {
    __shared__ u16 T[128][130];
    int blk = blockIdx.x;  // 4 b x 64 n-tiles
    int b = blk >> 6, nt = blk & 63;
    int n0 = nt * 128;
    int t = threadIdx.x;
#pragma unroll 4
    for (int it = 0; it < 64; ++it) {
        int idx = it * 256 + t;
        int c = idx >> 7, nl = idx & 127;
        T[nl][c] = f2b(fea[((size_t)(b * CH + c)) * NPTS + n0 + nl]);
    }
    __syncthreads();
#pragma unroll 4
    for (int it = 0; it < 64; ++it) {
        int idx = it * 256 + t;
        int nl = idx >> 7, c = idx & 127;
        feaT[((size_t)(b * NPTS + n0 + nl)) * CH + c] = T[nl][c];
    }
}

// ---------------- pp = |p|^2 (np.sum LTR), W pad to bf16 ----------------
__global__ __launch_bounds__(256) void kmisc(const float* __restrict__ coor,
                                             const float* __restrict__ W,
                                             float* __restrict__ pp,
                                             u16* __restrict__ Wpad) {
    int gid = blockIdx.x * 256 + threadIdx.x;
    if (blockIdx.x < 128) {
        int n = gid & 8191, b = gid >> 13;
        const float* cb = coor + b * 3 * NPTS;
        float x = cb[n], y = cb[NPTS + n], z = cb[2 * NPTS + n];
        pp[gid] = __fadd_rn(__fadd_rn(__fmul_rn(x, x), __fmul_rn(y, y)),
                            __fmul_rn(z, z));
    } else {
        int i = gid - 128 * 256;
        if (i < 256 * CINP) {
            int d = i / CINP, k = i - d * CINP;
            Wpad[i] = (k < 131) ? f2b(W[d * 131 + k]) : (u16)0;
        }
    }
}

// ---------------- spatial counting sort into 16 xy-bins (per batch) ----------------
__global__ __launch_bounds__(256) void ksort(const float* __restrict__ coor,
                                             float* __restrict__ sxg,
                                             float* __restrict__ syg,
                                             float* __restrict__ szg,
                                             int* __restrict__ sog) {
    __shared__ int hist[16], base[16];
    int b = blockIdx.x, tid = threadIdx.x;
    const float* cb = coor + b * 3 * NPTS;
    if (tid < 16) hist[tid] = 0;
    __syncthreads();
    int bins[32];
#pragma unroll 4
    for (int i = 0; i < 32; ++i) {
        int n = tid * 32 + i;
        float x = cb[n], y = cb[NPTS + n];
        int bx = min(3, (int)(x * 4.0f));
        int by = min(3, (int)(y * 4.0f));
        int bin = by * 4 + bx;
        bins[i] = bin;
        atomicAdd(&hist[bin], 1);
    }
    __syncthreads();
    if (tid == 0) {
        int acc = 0;
        for (int k2 = 0; k2 < 16; ++k2) { base[k2] = acc; acc += hist[k2]; hist[k2] = 0; }
    }
    __syncthreads();
#pragma unroll 4
    for (int i = 0; i < 32; ++i) {
        int n = tid * 32 + i;
        int bin = bins[i];
        int pos = base[bin] + atomicAdd(&hist[bin], 1);
        sxg[b * NPTS + pos] = cb[n];
        syg[b * NPTS + pos] = cb[NPTS + n];
        szg[b * NPTS + pos] = cb[2 * NPTS + n];
        sog[b * NPTS + pos] = n;
    }
}

// ---------------- FPS v4: 1 block (1024 thr) per batch ----------------
__global__ __launch_bounds__(1024) void kfps(const float* __restrict__ sxg,
                                             const float* __restrict__ syg,
                                             const float* __restrict__ szg,
                                             const int* __restrict__ sog,
                                             int* __restrict__ fpsIdx,
                                             float* __restrict__ outCoor) {
    __shared__ float4 sp[NPTS];          // 128 KB
    __shared__ unsigned sWin[SPTS];      // 8 KB
    __shared__ u64 sAtom[4];
    __shared__ int slot0s;
    int tid = threadIdx.x;
    int b = blockIdx.x;
    int lane = tid & 63;
    const float* gx = sxg + b * NPTS;
    const float* gy = syg + b * NPTS;
    const float* gz = szg + b * NPTS;
    const int* go = sog + b * NPTS;
    f32x2 X2[4], Y2[4], Z2[4], D2[4];
    unsigned PK[8];
    int n0 = tid * 8;
    if (tid < 4) sAtom[tid] = 0;
#pragma unroll
    for (int j = 0; j < 8; ++j) {
        float x = gx[n0 + j], y = gy[n0 + j], z = gz[n0 + j];
        sp[n0 + j] = make_float4(x, y, z, 0.0f);
        X2[j >> 1][j & 1] = x; Y2[j >> 1][j & 1] = y; Z2[j >> 1][j & 1] = z;
        D2[j >> 1][j & 1] = 1e10f;
        int oi = go[n0 + j];
        PK[j] = ((unsigned)oi << 16) | (unsigned)(n0 + j);
        if (oi == 0) slot0s = n0 + j;
    }
    // wave bbox (used conservatively; exactness irrelevant)
    float lox = X2[0][0], hix = lox, loy = Y2[0][0], hiy = loy, loz = Z2[0][0], hiz = loz;
#pragma unroll
    for (int j = 1; j < 8; ++j) {
        float x = X2[j >> 1][j & 1], y = Y2[j >> 1][j & 1], z = Z2[j >> 1][j & 1];
        lox = fminf(lox, x); hix = fmaxf(hix, x);
        loy = fminf(loy, y); hiy = fmaxf(hiy, y);
        loz = fminf(loz, z); hiz = fmaxf(hiz, z);
    }
#pragma unroll
    for (int off = 32; off > 0; off >>= 1) {
        lox = fminf(lox, __shfl_xor(lox, off)); hix = fmaxf(hix, __shfl_xor(hix, off));
        loy = fminf(loy, __shfl_xor(loy, off)); hiy = fmaxf(hiy, __shfl_xor(hiy, off));
        loz = fminf(loz, __shfl_xor(loz, off)); hiz = fmaxf(hiz, __shfl_xor(hiz, off));
    }
    __syncthreads();
    int far = slot0s;
    if (tid == 0) sWin[0] = (unsigned)slot0s;  // origIdx 0 in high bits
    float wMaxF = 3.4e38f;  // force update on first iteration
    u64 cachedKey = 1;      // any real key beats it
    for (int t = 1; t < SPTS; ++t) {
        float4 c = sp[far];  // uniform addr -> broadcast ds_read_b128
        float fx = c.x, fy = c.y, fz = c.z;
        // exact-no-op skip: min dist(c, wave bbox)^2 vs max D at last update
        float ddx = fmaxf(0.0f, fmaxf(lox - fx, fx - hix));
        float ddy = fmaxf(0.0f, fmaxf(loy - fy, fy - hiy));
        float ddz = fmaxf(0.0f, fmaxf(loz - fz, fz - hiz));
        float dmin2 = ddx * ddx + ddy * ddy + ddz * ddz;
        if (!(dmin2 * 0.9995f >= wMaxF)) {  // wave-uniform branch
            {
#pragma clang fp contract(off)
                f32x2 fx2 = {fx, fx}, fy2 = {fy, fy}, fz2 = {fz, fz};
#pragma unroll
                for (int i = 0; i < 4; ++i) {
                    f32x2 dx = X2[i] - fx2;
                    f32x2 dy = Y2[i] - fy2;
                    f32x2 dz = Z2[i] - fz2;
                    f32x2 s = (dx * dx + dy * dy) + dz * dz;  // per-elem RN, np order
                    D2[i][0] = fminf(D2[i][0], s[0]);
                    D2[i][1] = fminf(D2[i][1], s[1]);
                }
            }
            // thread argmax: value tree, then min-PK among ties
            float m01 = fmaxf(D2[0][0], D2[0][1]), m23 = fmaxf(D2[1][0], D2[1][1]);
            float m45 = fmaxf(D2[2][0], D2[2][1]), m67 = fmaxf(D2[3][0], D2[3][1]);
            float m = fmaxf(fmaxf(m01, m23), fmaxf(m45, m67));
            unsigned sel = 0xFFFFFFFFu;
#pragma unroll
            for (int j = 0; j < 8; ++j) {
                float dj = D2[j >> 1][j & 1];
                sel = (dj == m) ? (sel < PK[j] ? sel : PK[j]) : sel;
            }
            // wave value-max via DPP on float bits (all >= 0)
            unsigned mbits = __float_as_uint(m);
            unsigned r = mbits;
            r = dpp_maxu<0xB1>(r);    // quad_perm xor1
            r = dpp_maxu<0x4E>(r);    // quad_perm xor2
            r = dpp_maxu<0x141>(r);   // row_half_mirror
            r = dpp_maxu<0x140>(r);   // row_mirror
            r = dpp_maxu<0x142>(r);   // row_bcast:15
            r = dpp_maxu<0x143>(r);   // row_bcast:31
            unsigned wmaxb = (unsigned)__builtin_amdgcn_readlane((int)r, 63);
            u64 ball = __ballot(mbits == wmaxb);
            unsigned wpk;
            if (__popcll(ball) == 1) {  // unique winner lane (common)
                int l = __ffsll(ball) - 1;
                wpk = (unsigned)__builtin_amdgcn_readlane((int)sel, l);
            } else {                    // rare: cross-lane value tie
                u64 kk = (mbits == wmaxb) ? (((u64)wmaxb << 32) | (unsigned)~sel) : 0ull;
                kk = dpp_max64<0xB1>(kk);
                kk = dpp_max64<0x4E>(kk);
                kk = dpp_max64<0x141>(kk);
                kk = dpp_max64<0x140>(kk);
                kk = dpp_max64<0x142>(kk);
                kk = dpp_max64<0x143>(kk);
                unsigned lo = (unsigned)__builtin_amdgcn_readlane((int)(unsigned)kk, 63);
                wpk = ~lo;
            }
            cachedKey = ((u64)wmaxb << 32) | (unsigned)~wpk;
            wMaxF = __uint_as_float(wmaxb);
        }
        if (lane == 63) atomicMax(&sAtom[t & 3], cachedKey);
        if (tid == 0) sAtom[(t + 1) & 3] = 0;  // slot quiescent this window
        __syncthreads();
        u64 wk = sAtom[t & 3];  // broadcast ds_read_b64
        unsigned pk = ~(unsigned)wk;
        far = (int)(pk & 0xFFFFu);
        if (tid == 0) sWin[t] = pk;
    }
    __syncthreads();
    // deferred flush
    for (int i = tid; i < SPTS; i += 1024) {
        unsigned pk = sWin[i];
        int slot = (int)(pk & 0xFFFFu);
        float4 c = sp[slot];
        fpsIdx[b * SPTS + i] = (int)(pk >> 16);
        float* oc = outCoor + b * 3 * SPTS + i;
        oc[0] = c.x; oc[SPTS] = c.y; oc[2 * SPTS] = c.z;
    }
}

// ---------------- grouping (exact f32, GEMM-style FMA dot): 1 wave/row ----------------
__global__ __launch_bounds__(256) void kgroup(const float* __restrict__ coor,
                                              const float* __restrict__ pp,
                                              const int* __restrict__ fpsIdx,
                                              int* __restrict__ gidxOut) {
    __shared__ u64 buf[4][256];
    __shared__ int cnt[4];
    int tid = threadIdx.x;
    int wv = tid >> 6, lane = tid & 63;
    if (tid < 4) cnt[tid] = 0;
    __syncthreads();
    int row = blockIdx.x * 4 + wv;
    int b = row >> 11, s = row & 2047;
    const float* cb = coor + b * 3 * NPTS;
    int n0 = fpsIdx[b * SPTS + s];
    float cx = cb[n0], cy = cb[NPTS + n0], cz = cb[2 * NPTS + n0];
    float cc = __fadd_rn(__fadd_rn(__fmul_rn(cx, cx), __fmul_rn(cy, cy)),
                         __fmul_rn(cz, cz));
    const float* ppb = pp + b * NPTS;
    u64 mk = ~0ull;
    for (int n = lane; n < NPTS; n += 64) {
        float x = cb[n], y = cb[NPTS + n], z = cb[2 * NPTS + n];
        float dot = __fmaf_rn(cz, z, __fmaf_rn(cy, y, __fmul_rn(cx, x)));
        float sq = __fsub_rn(__fadd_rn(cc, ppb[n]), __fmul_rn(2.0f, dot));
        unsigned ub = __float_as_uint(sq);
        ub ^= (ub >> 31) ? 0xFFFFFFFFu : 0x80000000u;
        u64 key = ((u64)ub << 32) | (unsigned)n;
        mk = umin64(mk, key);
        if (sq <= 0.01f) {
            int p = atomicAdd(&cnt[wv], 1);
            if (p < 256) buf[wv][p] = key;
        }
    }
#pragma unroll
    for (int off = 32; off > 0; off >>= 1) mk = umin64(mk, __shfl_xor(mk, off));
    int C = cnt[wv];
    if (C > 256) C = 256;
    int* go = gidxOut + row * KN;
    if (C <= 32) {
        if (lane < 32) {
            unsigned idx = (lane < C) ? (unsigned)buf[wv][lane] : (unsigned)mk;
            go[lane] = (int)idx;
        }
    } else {
        u64 e[4];
#pragma unroll
        for (int i = 0; i < 4; ++i) {
            int j2 = lane + (i << 6);
            e[i] = (j2 < C) ? buf[wv][j2] : ~0ull;
        }
        int cl = 0;
        unsigned sel = 0;
        for (int it = 0; it < 32; ++it) {
            u64 lb = ~0ull;
            int li = 0;
#pragma unroll
            for (int i = 0; i < 4; ++i) {
                bool f = (((cl >> i) & 1) == 0) && (e[i] < lb);
                lb = f ? e[i] : lb;
                li = f ? i : li;
            }
            u64 wmin = lb;
#pragma unroll
            for (int off = 32; off > 0; off >>= 1) wmin = umin64(wmin, __shfl_xor(wmin, off));
            u64 bal = __ballot(lb == wmin);
            int src = __ffsll((unsigned long long)bal) - 1;
            if (lane == src) cl |= (1 << li);
            if (lane == it) sel = (unsigned)wmin;
        }
        if (lane < 32) go[lane] = (int)sel;
    }
}

// ---------------- MLP + BN + ReLU + maxpool: 1 block per (b,s) row ----------------
__global__ __launch_bounds__(256) void kfeat(const float* __restrict__ coor,
                                             const u16* __restrict__ feaT,
                                             const u16* __restrict__ Wpad,
                                             const float* __restrict__ bias,
                                             const float* __restrict__ gamma,
                                             const float* __restrict__ beta,
                                             const float* __restrict__ bmean,
                                             const float* __restrict__ bvar,
                                             const int* __restrict__ fpsIdx,
                                             const int* __restrict__ gidx,
                                             float* __restrict__ outFea) {
    __shared__ u16 g[KN][168];
    int row = blockIdx.x;
    int b = row >> 11, s = row & 2047;
    int tid = threadIdx.x;
    {
        int k = tid >> 3, j = tid & 7;
        const float* cb = coor + b * 3 * NPTS;
        int nc = fpsIdx[b * SPTS + s];
        int nbr = gidx[row * KN + k];
        const uint4* f4 = (const uint4*)(feaT + (((size_t)b * NPTS + nbr) << 7));
        uint4* gr = (uint4*)&g[k][0];
        gr[j] = f4[j];
        gr[j + 8] = f4[j + 8];
        for (int c = 128 + j; c < CINP; c += 8) {
            u16 v = 0;
            if (c < 131) {
                int dim = c - 128;
                float pv = cb[dim * NPTS + nbr];
                float cv = cb[dim * NPTS + nc];
                v = f2b(__fdiv_rn(__fsub_rn(pv, cv), 0.1f));
            }
            g[k][c] = v;
        }
    }
    __syncthreads();
    int w = tid >> 6, lane = tid & 63;
    int mrow = lane & 15, q = lane >> 4;
    f32x4 acc[4][2] = {};
#pragma unroll
    for (int ks = 0; ks < 5; ++ks) {
        int kb = ks * 32 + q * 8;
        bf16x8 b0 = *(const bf16x8*)&g[mrow][kb];
        bf16x8 b1 = *(const bf16x8*)&g[mrow + 16][kb];
#pragma unroll
        for (int mt = 0; mt < 4; ++mt) {
            bf16x8 a = *(const bf16x8*)&Wpad[(size_t)(w * 64 + mt * 16 + mrow) * CINP + kb];
            acc[mt][0] = __builtin_amdgcn_mfma_f32_16x16x32_bf16(a, b0, acc[mt][0], 0, 0, 0);
            acc[mt][1] = __builtin_amdgcn_mfma_f32_16x16x32_bf16(a, b1, acc[mt][1], 0, 0, 0);
        }
    }
#pragma unroll
    for (int mt = 0; mt < 4; ++mt) {
#pragma unroll
        for (int r = 0; r < 4; ++r) {
            int m = w * 64 + mt * 16 + q * 4 + r;
            float ga = gamma[m], be = beta[m];
            float mu = bmean[m], va = bvar[m], bi = bias[m];
            float rs = 1.0f / sqrtf(va + 1e-5f);
            float h0 = acc[mt][0][r] + bi;
            h0 = fmaxf(ga * (h0 - mu) * rs + be, 0.0f);
            float h1 = acc[mt][1][r] + bi;
            h1 = fmaxf(ga * (h1 - mu) * rs + be, 0.0f);
            float v = fmaxf(h0, h1);
#pragma unroll
            for (int off = 1; off < 16; off <<= 1) v = fmaxf(v, __shfl_xor(v, off));
            if (mrow == 0) outFea[((size_t)(b * 256 + m)) * SPTS + s] = v;
        }
    }
}

extern "C" void kernel_launch(void* const* d_in, const int* in_sizes, int n_in,
                              void* d_out, int out_size, void* d_ws, size_t ws_size,
                              hipStream_t stream) {
    const float* coor = (const float*)d_in[0];
    const float* fea = (const float*)d_in[1];
    const float* W = (const float*)d_in[2];
    const float* bias = (const float*)d_in[3];
    const float* gamma = (const float*)d_in[4];
    const float* beta = (const float*)d_in[5];
    const float* bmean = (const float*)d_in[6];
    const float* bvar = (const float*)d_in[7];
    char* ws = (char*)d_ws;
    int* fpsIdx = (int*)ws;                              // 32 KB
    int* gidx = (int*)(ws + 32768);                      // 1 MB
    float* pp = (float*)(ws + 32768 + 1048576);          // 128 KB
    u16* feaT = (u16*)(ws + 1212416);                    // 8 MB bf16
    u16* Wpad = (u16*)(ws + 9601024);                    // 80 KB bf16
    float* sxg = (float*)(ws + 9682944);                 // 128 KB
    float* syg = (float*)(ws + 9814016);                 // 128 KB
    float* szg = (float*)(ws + 9945088);                 // 128 KB
    int* sog = (int*)(ws + 10076160);                    // 128 KB
    float* outC = (float*)d_out;                         // (B,3,S) f32
    float* outF = outC + NB * 3 * SPTS;                  // (B,2C,S) f32

    ktrans<<<256, 256, 0, stream>>>(fea, feaT);
    kmisc<<<288, 256, 0, stream>>>(coor, W, pp, Wpad);
    ksort<<<NB, 256, 0, stream>>>(coor, sxg, syg, szg, sog);
    kfps<<<NB, 1024, 0, stream>>>(sxg, syg, szg, sog, fpsIdx, outC);
    kgroup<<<2048, 256, 0, stream>>>(coor, pp, fpsIdx, gidx);
    kfeat<<<8192, 256, 0, stream>>>(coor, feaT, Wpad, bias, gamma, beta, bmean, bvar,
                                    fpsIdx, gidx, outF);
}